// Round 12
// baseline (1884.609 us; speedup 1.0000x reference)
//
#include <hip/hip_runtime.h>
#include <hip/hip_bf16.h>

#define B   64
#define T   512
#define DIN 64
#define F   64
#define U   128
#define G3  384     // 3U
#define M2  256     // 2U
#define NH  4
#define KD  128
#define HD  512     // NH*KD
#define BT  (B*T)   // 32768

typedef __attribute__((ext_vector_type(8))) short short8;
typedef __attribute__((ext_vector_type(4))) float floatx4;
typedef __attribute__((ext_vector_type(4))) unsigned short ushort4_t;
typedef __attribute__((ext_vector_type(2))) unsigned short ushort2_t;
typedef __hip_bfloat16 bf16;

// ---------------- fused weight transpose+cast: 8 segments, one launch ----------------
__device__ __forceinline__ void wcast_seg(const float* __restrict__ src,
        bf16* __restrict__ dst, int K, int N, int i)
{
    if (i < K*N) {
        const int k = i / N, n = i - k*N;
        dst[n*K + k] = __float2bfloat16(src[i]);
    }
}

__global__ __launch_bounds__(256) void k_wcast_all(
        const float* __restrict__ s0, const float* __restrict__ s1,
        const float* __restrict__ s2, const float* __restrict__ s3,
        const float* __restrict__ s4, const float* __restrict__ s5,
        const float* __restrict__ s6, const float* __restrict__ s7,
        bf16* __restrict__ wb)
{
    const int i = blockIdx.x*256 + threadIdx.x;
    switch (blockIdx.y) {
        case 0: wcast_seg(s0, wb,          64,  384, i); break;
        case 1: wcast_seg(s1, wb + 24576,  64,  384, i); break;
        case 2: wcast_seg(s2, wb + 49152,  256, 512, i); break;
        case 3: wcast_seg(s3, wb + 180224, 256, 512, i); break;
        case 4: wcast_seg(s4, wb + 311296, 256, 512, i); break;
        case 5: wcast_seg(s5, wb + 442368, 512, 256, i); break;
        case 6: wcast_seg(s6, wb + 573440, 256, 384, i); break;
        case 7: wcast_seg(s7, wb + 671744, 256, 384, i); break;
    }
}

// ---------------- conv1d(same,k=3) + BN(inference) + ReLU -> bf16 ----------------
__global__ __launch_bounds__(256) void k_conv(const float* __restrict__ in,
        const float* __restrict__ cw, const float* __restrict__ cb,
        const float* __restrict__ gamma, const float* __restrict__ beta,
        const float* __restrict__ mean, const float* __restrict__ var,
        bf16* __restrict__ x1h)
{
    __shared__ float w_s[3*64*64];   // 48 KB
    __shared__ float in_s[18*64];
    const int b  = blockIdx.y;
    const int t0 = blockIdx.x * 16;
    const int tid = threadIdx.x;
    for (int idx = tid; idx < 3*64*64; idx += 256) w_s[idx] = cw[idx];
    for (int idx = tid; idx < 18*64; idx += 256) {
        int row = idx >> 6;
        int d   = idx & 63;
        int t   = t0 - 1 + row;
        in_s[idx] = (t >= 0 && t < T) ? in[((size_t)b*T + t)*DIN + d] : 0.0f;
    }
    __syncthreads();
    const int f  = tid & 63;
    const int tl = tid >> 6;   // 0..3
    const float scale = gamma[f] * rsqrtf(var[f] + 1e-3f);
    const float shift = beta[f] - mean[f] * scale;
    const float bias  = cb[f];
    for (int q = 0; q < 4; ++q) {
        const int tt = tl*4 + q;   // 0..15
        float acc = bias;
        for (int tap = 0; tap < 3; ++tap) {
            const float* irow = &in_s[(tt + tap)*64];
            const float* wrow = &w_s[tap*64*64 + f];
            #pragma unroll 16
            for (int d = 0; d < 64; ++d) acc += irow[d] * wrow[d*64];
        }
        float v = acc * scale + shift;
        x1h[((size_t)b*T + t0 + tt)*F + f] = __float2bfloat16(fmaxf(v, 0.0f));
    }
}

// ------------- MFMA bf16 GEMM: C[R,N] = A[R,K] @ Bt[N,K]^T + bias (+resid) -------------
__global__ __launch_bounds__(256) void k_gemm(const bf16* __restrict__ A,
        const bf16* __restrict__ Bt, const float* __restrict__ bias,
        const bf16* __restrict__ resid, float* __restrict__ outF,
        bf16* __restrict__ outH, int K, int N, int biasRow)
{
    __shared__ short As[128*32];   // 8 KB
    __shared__ short Bs[128*32];   // 8 KB
    const int nbase = blockIdx.x * 128;
    const int rbase = blockIdx.y * 128;
    const int tid  = threadIdx.x;
    const int lane = tid & 63;
    const int wv   = tid >> 6;
    const int wm   = wv & 1;        // row half
    const int wn   = wv >> 1;       // col half
    const int l16  = lane & 15;
    const int quad = lane >> 4;

    floatx4 acc[4][4];
    #pragma unroll
    for (int i = 0; i < 4; ++i)
        #pragma unroll
        for (int j = 0; j < 4; ++j) acc[i][j] = (floatx4)0.0f;

    const int row  = tid >> 1;           // staging: 2 threads per tile-row
    const int koff = (tid & 1) * 16;     // 16 bf16 = 32 B per thread
    const int nK = K >> 5;
    for (int kt = 0; kt < nK; ++kt) {
        if (kt) __syncthreads();
        {
            const float4* ga = reinterpret_cast<const float4*>(
                &A[(size_t)(rbase + row)*K + kt*32 + koff]);
            const float4 a0 = ga[0], a1 = ga[1];
            const float4* gb = reinterpret_cast<const float4*>(
                &Bt[(size_t)(nbase + row)*K + kt*32 + koff]);
            const float4 b0 = gb[0], b1 = gb[1];
            float4* la = reinterpret_cast<float4*>(&As[row*32 + koff]);
            la[0] = a0; la[1] = a1;
            float4* lb = reinterpret_cast<float4*>(&Bs[row*32 + koff]);
            lb[0] = b0; lb[1] = b1;
        }
        __syncthreads();
        short8 af[4], bf[4];
        #pragma unroll
        for (int i = 0; i < 4; ++i)
            af[i] = *reinterpret_cast<const short8*>(&As[(wm*64 + i*16 + l16)*32 + quad*8]);
        #pragma unroll
        for (int j = 0; j < 4; ++j)
            bf[j] = *reinterpret_cast<const short8*>(&Bs[(wn*64 + j*16 + l16)*32 + quad*8]);
        #pragma unroll
        for (int i = 0; i < 4; ++i)
            #pragma unroll
            for (int j = 0; j < 4; ++j)
                acc[i][j] = __builtin_amdgcn_mfma_f32_16x16x32_bf16(af[i], bf[j], acc[i][j], 0, 0, 0);
    }

    #pragma unroll
    for (int j = 0; j < 4; ++j) {
        const int gcol = nbase + wn*64 + j*16 + l16;
        const float bj = biasRow ? 0.0f : bias[gcol];
        #pragma unroll
        for (int i = 0; i < 4; ++i) {
            #pragma unroll
            for (int r = 0; r < 4; ++r) {
                const int grow = rbase + wm*64 + i*16 + quad*4 + r;
                const size_t off = (size_t)grow*N + gcol;
                float v = acc[i][j][r] + (biasRow ? bias[grow] : bj);
                if (resid) v += __bfloat162float(resid[off]);
                if (outF) outF[off] = v;
                if (outH) outH[off] = __float2bfloat16(v);
            }
        }
    }
}

// ------------- paired GEMM: same A, two (Bt, bias, out) sets, blockIdx.z selects -------------
__global__ __launch_bounds__(256) void k_gemm2(const bf16* __restrict__ A,
        const bf16* __restrict__ Bt0, const bf16* __restrict__ Bt1,
        const float* __restrict__ bias0, const float* __restrict__ bias1,
        bf16* __restrict__ out0, bf16* __restrict__ out1, int K, int N)
{
    const bf16* Bt    = blockIdx.z ? Bt1 : Bt0;
    const float* bias = blockIdx.z ? bias1 : bias0;
    bf16* outH        = blockIdx.z ? out1 : out0;

    __shared__ short As[128*32];
    __shared__ short Bs[128*32];
    const int nbase = blockIdx.x * 128;
    const int rbase = blockIdx.y * 128;
    const int tid  = threadIdx.x;
    const int lane = tid & 63;
    const int wv   = tid >> 6;
    const int wm   = wv & 1;
    const int wn   = wv >> 1;
    const int l16  = lane & 15;
    const int quad = lane >> 4;

    floatx4 acc[4][4];
    #pragma unroll
    for (int i = 0; i < 4; ++i)
        #pragma unroll
        for (int j = 0; j < 4; ++j) acc[i][j] = (floatx4)0.0f;

    const int row  = tid >> 1;
    const int koff = (tid & 1) * 16;
    const int nK = K >> 5;
    for (int kt = 0; kt < nK; ++kt) {
        if (kt) __syncthreads();
        {
            const float4* ga = reinterpret_cast<const float4*>(
                &A[(size_t)(rbase + row)*K + kt*32 + koff]);
            const float4 a0 = ga[0], a1 = ga[1];
            const float4* gb = reinterpret_cast<const float4*>(
                &Bt[(size_t)(nbase + row)*K + kt*32 + koff]);
            const float4 b0 = gb[0], b1 = gb[1];
            float4* la = reinterpret_cast<float4*>(&As[row*32 + koff]);
            la[0] = a0; la[1] = a1;
            float4* lb = reinterpret_cast<float4*>(&Bs[row*32 + koff]);
            lb[0] = b0; lb[1] = b1;
        }
        __syncthreads();
        short8 af[4], bf[4];
        #pragma unroll
        for (int i = 0; i < 4; ++i)
            af[i] = *reinterpret_cast<const short8*>(&As[(wm*64 + i*16 + l16)*32 + quad*8]);
        #pragma unroll
        for (int j = 0; j < 4; ++j)
            bf[j] = *reinterpret_cast<const short8*>(&Bs[(wn*64 + j*16 + l16)*32 + quad*8]);
        #pragma unroll
        for (int i = 0; i < 4; ++i)
            #pragma unroll
            for (int j = 0; j < 4; ++j)
                acc[i][j] = __builtin_amdgcn_mfma_f32_16x16x32_bf16(af[i], bf[j], acc[i][j], 0, 0, 0);
    }

    #pragma unroll
    for (int j = 0; j < 4; ++j) {
        const int gcol = nbase + wn*64 + j*16 + l16;
        const float bj = bias[gcol];
        #pragma unroll
        for (int i = 0; i < 4; ++i) {
            #pragma unroll
            for (int r = 0; r < 4; ++r) {
                const int grow = rbase + wm*64 + i*16 + quad*4 + r;
                outH[(size_t)grow*N + gcol] = __float2bfloat16(acc[i][j][r] + bj);
            }
        }
    }
}

// ---------------- MFMA-batched GRU scan (wave-pair: 16 waves, split gate math) ----------------
__device__ __forceinline__ float sigmoidf_(float x){ return 1.0f/(1.0f + __expf(-x)); }
__device__ __forceinline__ float tanhf_(float x){ return 2.0f/(1.0f + __expf(-2.0f*x)) - 1.0f; }
__device__ __forceinline__ float bfbits2f(unsigned short u){
    return __uint_as_float(((unsigned)u) << 16);
}

// Block = 16 batches x 1 dir; grid (4,2) = 8 blocks (1 chain/CU). 1024 thr = 16 waves
// = 4 waves/SIMD (r11 showed the step is STALL-bound at 2 waves/SIMD, not issue-bound).
// Wave pair (grp = wv>>1) both issue the same 12 MFMA + same conflict-free hfrag
// reads (matrix/LDS pipes have headroom); sub = wv&1 splits the gate math: sub=0
// takes C-rows {0,1}, sub=1 takes {2,3} -> per-lane transcendentals halve and
// 4 waves/SIMD cover each other's exp/rcp dependency stalls.
// h in FRAGMENT ORDER (2048 shorts/tile), lgkm-only barrier, pointer-increment
// xg/yseq streams, depth-2 prefetch, bias rides as MFMA C-operand.
__global__ __launch_bounds__(1024, 1) void k_gru(const bf16* __restrict__ xg_f,
        const bf16* __restrict__ xg_b, const float* __restrict__ wh_f,
        const float* __restrict__ wh_b, const float* __restrict__ b_f,
        const float* __restrict__ b_b, bf16* __restrict__ yseq,
        float* __restrict__ hout)
{
    const int dir   = blockIdx.y;
    const int bbase = blockIdx.x * 16;
    const bf16* xg  = dir ? xg_b : xg_f;            // [B*T, 3U]
    const float* wh = dir ? wh_b : wh_f;            // [U, 3U]
    const float* bh = (dir ? b_b : b_f) + G3;       // b[1]
    const int tid  = threadIdx.x;
    const int lane = tid & 63;
    const int wv   = tid >> 6;       // 0..15
    const int grp  = wv >> 1;        // col-group 0..7 (16 gate cols each)
    const int sub  = wv & 1;         // row-half of the 4 C-rows
    const int l16  = lane & 15;
    const int quad = lane >> 4;
    const int cb2  = grp*16 + quad*4 + sub*2;   // this lane's 2 gate cols
    const int brow = bbase + l16;               // this lane's batch

    // W^T A-frags (pair-waves load identical copies; 48 VGPR)
    short8 wfrag[3][4];
    #pragma unroll
    for (int g = 0; g < 3; ++g)
        #pragma unroll
        for (int kt = 0; kt < 4; ++kt)
            #pragma unroll
            for (int j = 0; j < 8; ++j)
                reinterpret_cast<bf16*>(&wfrag[g][kt])[j] = __float2bfloat16(
                    wh[(size_t)(kt*32 + quad*8 + j)*G3 + g*U + grp*16 + l16]);

    // recurrent bias as preserved MFMA C-operands (all 4 rows; wave uses 2)
    floatx4 bz4, br4, bn4;
    #pragma unroll
    for (int r = 0; r < 4; ++r) {
        bz4[r] = bh[      grp*16 + quad*4 + r];
        br4[r] = bh[U   + grp*16 + quad*4 + r];
        bn4[r] = bh[2*U + grp*16 + quad*4 + r];
    }

    // b32 write index (shorts) for this lane's 2-col hnew store (cb2 even)
    const int wr_idx = ((cb2>>5)*64 + ((cb2>>3)&3)*16 + l16)*8 + (cb2&7);

    __shared__ __align__(16) short hbuf[2][2048];   // [parity][frag order]
    for (int i = tid; i < 2*2048; i += 1024) (&hbuf[0][0])[i] = 0;
    __syncthreads();

    float hprev0 = 0.f, hprev1 = 0.f;

    // pointer-increment streams
    const int t0 = dir ? T-1 : 0;
    const ptrdiff_t xstr = dir ? -(ptrdiff_t)G3 : (ptrdiff_t)G3;
    const ptrdiff_t ystr = dir ? -(ptrdiff_t)M2 : (ptrdiff_t)M2;
    const bf16* xp = xg + ((size_t)brow*T + t0)*G3 + cb2;
    bf16* yp = yseq ? (yseq + ((size_t)brow*T + t0)*M2 + dir*U + cb2) : nullptr;

    // depth-2 xg prefetch (2 cols per lane)
    ushort2_t xs[2][3];
    #pragma unroll
    for (int s = 0; s < 2; ++s) {
        xs[s][0] = *reinterpret_cast<const ushort2_t*>(xp);
        xs[s][1] = *reinterpret_cast<const ushort2_t*>(xp + U);
        xs[s][2] = *reinterpret_cast<const ushort2_t*>(xp + 2*U);
        xp += xstr;
    }

    for (int step2 = 0; step2 < T; step2 += 2) {
        #pragma unroll
        for (int u = 0; u < 2; ++u) {
            // B-frags: conflict-free lane-contiguous b128 reads (full h; all waves)
            short8 hfrag[4];
            #pragma unroll
            for (int kt = 0; kt < 4; ++kt)
                hfrag[kt] = *reinterpret_cast<const short8*>(
                    &hbuf[u][(kt*64 + lane)*8]);
            floatx4 az = __builtin_amdgcn_mfma_f32_16x16x32_bf16(wfrag[0][0], hfrag[0], bz4, 0, 0, 0);
            floatx4 ar = __builtin_amdgcn_mfma_f32_16x16x32_bf16(wfrag[1][0], hfrag[0], br4, 0, 0, 0);
            floatx4 an = __builtin_amdgcn_mfma_f32_16x16x32_bf16(wfrag[2][0], hfrag[0], bn4, 0, 0, 0);
            #pragma unroll
            for (int kt = 1; kt < 4; ++kt) {
                az = __builtin_amdgcn_mfma_f32_16x16x32_bf16(wfrag[0][kt], hfrag[kt], az, 0, 0, 0);
                ar = __builtin_amdgcn_mfma_f32_16x16x32_bf16(wfrag[1][kt], hfrag[kt], ar, 0, 0, 0);
                an = __builtin_amdgcn_mfma_f32_16x16x32_bf16(wfrag[2][kt], hfrag[kt], an, 0, 0, 0);
            }
            // select this wave's 2 rows (sub is wave-uniform; 6 cndmasks)
            const float azs0 = sub ? az[2] : az[0], azs1 = sub ? az[3] : az[1];
            const float ars0 = sub ? ar[2] : ar[0], ars1 = sub ? ar[3] : ar[1];
            const float ans0 = sub ? an[2] : an[0], ans1 = sub ? an[3] : an[1];
            // consume this step's xg (loaded 2 steps ago)
            const float xz0 = bfbits2f(xs[u][0][0]), xz1 = bfbits2f(xs[u][0][1]);
            const float xr0 = bfbits2f(xs[u][1][0]), xr1 = bfbits2f(xs[u][1][1]);
            const float xn0 = bfbits2f(xs[u][2][0]), xn1 = bfbits2f(xs[u][2][1]);
            // refill slot u (free-running pointer; <=2-row overrun is in-bounds of ws)
            xs[u][0] = *reinterpret_cast<const ushort2_t*>(xp);
            xs[u][1] = *reinterpret_cast<const ushort2_t*>(xp + U);
            xs[u][2] = *reinterpret_cast<const ushort2_t*>(xp + 2*U);
            xp += xstr;
            // gates + state update (batch brow, cols cb2, cb2+1)
            const float z0 = sigmoidf_(xz0 + azs0);
            const float r0 = sigmoidf_(xr0 + ars0);
            const float n0 = tanhf_(xn0 + r0*ans0);
            const float h0 = z0*hprev0 + (1.0f - z0)*n0;
            const float z1 = sigmoidf_(xz1 + azs1);
            const float r1 = sigmoidf_(xr1 + ars1);
            const float n1 = tanhf_(xn1 + r1*ans1);
            const float h1 = z1*hprev1 + (1.0f - z1)*n1;
            hprev0 = h0;  hprev1 = h1;
            bf16 hb0 = __float2bfloat16(h0);
            bf16 hb1 = __float2bfloat16(h1);
            const unsigned pk = (unsigned)*reinterpret_cast<unsigned short*>(&hb0)
                              | ((unsigned)*reinterpret_cast<unsigned short*>(&hb1) << 16);
            *reinterpret_cast<unsigned*>(&hbuf[u^1][wr_idx]) = pk;
            if (yp) {
                *reinterpret_cast<unsigned*>(yp) = pk;
                yp += ystr;
            }
            // LDS-only barrier: wait lgkmcnt(0), leave vmcnt in flight
            asm volatile("" ::: "memory");
            __builtin_amdgcn_s_waitcnt(0xC07F);
            __builtin_amdgcn_s_barrier();
            asm volatile("" ::: "memory");
        }
    }
    if (hout) {
        float2 hv = make_float2(hprev0, hprev1);
        *reinterpret_cast<float2*>(&hout[(size_t)brow*M2 + dir*U + cb2]) = hv;
    }
}

// ---------------- MFMA flash attention ----------------
// Q,K,O: [B*T, HD] bf16 (head h at col h*KD). VT: [HD, B*T] bf16 (transposed V).
__global__ __launch_bounds__(256) void k_attn(const bf16* __restrict__ Q,
        const bf16* __restrict__ Kp, const bf16* __restrict__ VT,
        bf16* __restrict__ O)
{
    __shared__ short k_s[64*136];    // 17408 B
    __shared__ short vt_s[128*72];   // 18432 B
    __shared__ short p_s[64*72];     //  9216 B
    const int qt = blockIdx.x;       // 0..7
    const int b  = blockIdx.y;
    const int h  = blockIdx.z;
    const int tid  = threadIdx.x;
    const int lane = tid & 63;
    const int wv   = tid >> 6;
    const int l16  = lane & 15;
    const int quad = lane >> 4;

    short8 qfrag[4];
    {
        const size_t qoff = (size_t)(b*T + qt*64 + wv*16 + l16)*HD + h*KD + quad*8;
        #pragma unroll
        for (int kt = 0; kt < 4; ++kt)
            qfrag[kt] = *reinterpret_cast<const short8*>(&Q[qoff + kt*32]);
    }

    floatx4 Oa[8];
    #pragma unroll
    for (int nf = 0; nf < 8; ++nf) Oa[nf] = (floatx4)0.0f;
    float mrun = -1e30f, lrun = 0.0f;

    for (int kg = 0; kg < 8; ++kg) {
        __syncthreads();
        #pragma unroll
        for (int it = 0; it < 4; ++it) {
            const int linear = it*256 + tid;
            const int key = linear >> 4;
            const int dc  = linear & 15;
            const float4 v = *reinterpret_cast<const float4*>(
                &Kp[(size_t)(b*T + kg*64 + key)*HD + h*KD + dc*8]);
            *reinterpret_cast<float4*>(&k_s[key*136 + dc*8]) = v;
        }
        #pragma unroll
        for (int it = 0; it < 4; ++it) {
            const int linear = it*256 + tid;
            const int d  = linear >> 3;
            const int kc = linear & 7;
            const float4 v = *reinterpret_cast<const float4*>(
                &VT[(size_t)(h*KD + d)*BT + b*T + kg*64 + kc*8]);
            *reinterpret_cast<float4*>(&vt_s[d*72 + kc*8]) = v;
        }
        __syncthreads();
        floatx4 s[4];
        #pragma unroll
        for (int kb = 0; kb < 4; ++kb) s[kb] = (floatx4)0.0f;
        #pragma unroll
        for (int kt = 0; kt < 4; ++kt) {
            #pragma unroll
            for (int kb = 0; kb < 4; ++kb) {
                const short8 af = *reinterpret_cast<const short8*>(
                    &k_s[(kb*16 + l16)*136 + kt*32 + quad*8]);
                s[kb] = __builtin_amdgcn_mfma_f32_16x16x32_bf16(af, qfrag[kt], s[kb], 0, 0, 0);
            }
        }
        float kmax = -1e30f;
        #pragma unroll
        for (int kb = 0; kb < 4; ++kb)
            #pragma unroll
            for (int r = 0; r < 4; ++r) {
                s[kb][r] *= 0.08838834764831845f;
                kmax = fmaxf(kmax, s[kb][r]);
            }
        kmax = fmaxf(kmax, __shfl_xor(kmax, 16));
        kmax = fmaxf(kmax, __shfl_xor(kmax, 32));
        const float mnew  = fmaxf(mrun, kmax);
        const float alpha = __expf(mrun - mnew);
        float psum = 0.0f;
        #pragma unroll
        for (int kb = 0; kb < 4; ++kb)
            #pragma unroll
            for (int r = 0; r < 4; ++r) {
                const float p = __expf(s[kb][r] - mnew);
                s[kb][r] = p;
                psum += p;
            }
        psum += __shfl_xor(psum, 16);
        psum += __shfl_xor(psum, 32);
        lrun = lrun*alpha + psum;
        mrun = mnew;
        #pragma unroll
        for (int r = 0; r < 4; ++r) {
            const float ar = __shfl(alpha, quad*4 + r);
            #pragma unroll
            for (int nf = 0; nf < 8; ++nf) Oa[nf][r] *= ar;
        }
        bf16* pb = reinterpret_cast<bf16*>(p_s);
        #pragma unroll
        for (int kb = 0; kb < 4; ++kb)
            #pragma unroll
            for (int r = 0; r < 4; ++r)
                pb[(wv*16 + l16)*72 + kb*16 + quad*4 + r] = __float2bfloat16(s[kb][r]);
        #pragma unroll
        for (int kt2 = 0; kt2 < 2; ++kt2) {
            const short8 pf = *reinterpret_cast<const short8*>(
                &p_s[(wv*16 + l16)*72 + kt2*32 + quad*8]);
            #pragma unroll
            for (int nf = 0; nf < 8; ++nf) {
                const short8 vf = *reinterpret_cast<const short8*>(
                    &vt_s[(nf*16 + l16)*72 + kt2*32 + quad*8]);
                Oa[nf] = __builtin_amdgcn_mfma_f32_16x16x32_bf16(pf, vf, Oa[nf], 0, 0, 0);
            }
        }
    }
    float linv[4];
    #pragma unroll
    for (int r = 0; r < 4; ++r) linv[r] = 1.0f / __shfl(lrun, quad*4 + r);
    #pragma unroll
    for (int nf = 0; nf < 8; ++nf)
        #pragma unroll
        for (int r = 0; r < 4; ++r) {
            const size_t row = (size_t)(b*T + qt*64 + wv*16 + quad*4 + r);
            O[row*HD + h*KD + nf*16 + l16] = __float2bfloat16(Oa[nf][r] * linv[r]);
        }
}

// ---------------- dense head ----------------
__global__ void k_dense(const float* __restrict__ h2, const float* __restrict__ dw,
                        const float* __restrict__ db, float* __restrict__ out)
{
    const int b = threadIdx.x;
    float acc = db[0];
    for (int mm = 0; mm < M2; ++mm) acc += h2[b*M2 + mm] * dw[mm];
    out[b] = acc;
}

extern "C" void kernel_launch(void* const* d_in, const int* in_sizes, int n_in,
                              void* d_out, int out_size, void* d_ws, size_t ws_size,
                              hipStream_t stream)
{
    const float* inputs  = (const float*)d_in[0];
    const float* conv_w  = (const float*)d_in[1];
    const float* conv_b  = (const float*)d_in[2];
    const float* bn_g    = (const float*)d_in[3];
    const float* bn_b    = (const float*)d_in[4];
    const float* bn_m    = (const float*)d_in[5];
    const float* bn_v    = (const float*)d_in[6];
    const float* g1f_wx  = (const float*)d_in[7];
    const float* g1f_wh  = (const float*)d_in[8];
    const float* g1f_b   = (const float*)d_in[9];
    const float* g1b_wx  = (const float*)d_in[10];
    const float* g1b_wh  = (const float*)d_in[11];
    const float* g1b_b   = (const float*)d_in[12];
    const float* wq      = (const float*)d_in[13];
    const float* bq      = (const float*)d_in[14];
    const float* wk      = (const float*)d_in[15];
    const float* bk      = (const float*)d_in[16];
    const float* wv_     = (const float*)d_in[17];
    const float* bv      = (const float*)d_in[18];
    const float* wo      = (const float*)d_in[19];
    const float* bo      = (const float*)d_in[20];
    const float* g2f_wx  = (const float*)d_in[21];
    const float* g2f_wh  = (const float*)d_in[22];
    const float* g2f_b   = (const float*)d_in[23];
    const float* g2b_wx  = (const float*)d_in[24];
    const float* g2b_wh  = (const float*)d_in[25];
    const float* g2b_b   = (const float*)d_in[26];
    const float* dense_w = (const float*)d_in[27];
    const float* dense_b = (const float*)d_in[28];
    float* out = (float*)d_out;
    (void)in_sizes; (void)n_in; (void)out_size; (void)ws_size;

    // ---- workspace (float-slot offsets into 128 MiB = 33,554,432 fslots) ----
    float* ws = (float*)d_ws;
    bf16* wb = (bf16*)ws;
    bf16* g1fT = wb;            // [384,64]
    bf16* g1bT = wb + 24576;
    bf16* wqT  = wb + 49152;    // [512,256]
    bf16* wkT  = wb + 180224;
    bf16* wvT  = wb + 311296;   // [512,256] -> GEMM-A for V^T
    bf16* woT  = wb + 442368;   // [256,512]
    bf16* g2fT = wb + 573440;   // [384,256]
    bf16* g2bT = wb + 671744;   // ends 770048 < 786432

    bf16*  x1h  = (bf16*)(ws + 393216);     // [B*T,64]
    bf16*  xg1f = (bf16*)(ws + 1441792);    // [B*T,384] bf16
    bf16*  xg1b = (bf16*)(ws + 7733248);    // [B*T,384] bf16
    bf16*  y1h  = (bf16*)(ws + 26607616);   // [B*T,256]
    bf16*  qh   = (bf16*)(ws + 393216);     // [B*T,512]
    bf16*  kh   = (bf16*)(ws + 8781824);    // [B*T,512]
    bf16*  vtg  = (bf16*)(ws + 17170432);   // [512, B*T]
    bf16*  Oh   = qh;                       // attention output in-place
    bf16*  x2h  = (bf16*)(ws + 17170432);   // [B*T,256] (over dead vtg)
    bf16*  xg2f = (bf16*)(ws + 393216);     // [B*T,384]
    bf16*  xg2b = (bf16*)(ws + 6684672);
    float* h2   = ws + 12976128;            // [B,256]

    // 0. fused weight casts (one launch)
    k_wcast_all<<<dim3(512, 8), 256, 0, stream>>>(g1f_wx, g1b_wx, wq, wk, wv_,
                                                  wo, g2f_wx, g2b_wx, wb);

    // 1. conv + BN + ReLU -> x1h
    k_conv<<<dim3(T/16, B), 256, 0, stream>>>(inputs, conv_w, conv_b,
                                              bn_g, bn_b, bn_m, bn_v, x1h);
    // 2. GRU1 input gates, fwd+bwd in one launch
    k_gemm2<<<dim3(3, 256, 2), 256, 0, stream>>>(x1h, g1fT, g1bT, g1f_b, g1b_b,
                                                 xg1f, xg1b, 64, G3);
    // 3. GRU1 scan -> y1h  (wave-pair, 1024 thr, 1 chain/CU)
    k_gru<<<dim3(4, 2), 1024, 0, stream>>>(xg1f, xg1b, g1f_wh, g1b_wh,
                                           g1f_b, g1b_b, y1h, nullptr);
    // 4. Q,K in one launch; V as transposed GEMM
    k_gemm2<<<dim3(4, 256, 2), 256, 0, stream>>>(y1h, wqT, wkT, bq, bk,
                                                 qh, kh, 256, HD);
    k_gemm<<<dim3(BT/128, 4), 256, 0, stream>>>(wvT, y1h, bv, nullptr, nullptr, vtg, 256, BT, 1);
    // 5. MFMA flash attention, O in-place over Q
    k_attn<<<dim3(T/64, B, NH), 256, 0, stream>>>(qh, kh, vtg, Oh);
    // 6. output projection + bias + residual(y1h) -> x2h
    k_gemm<<<dim3(2, 256), 256, 0, stream>>>(Oh, woT, bo, y1h, nullptr, x2h, HD, M2, 0);
    // 7. GRU2 input gates, fwd+bwd in one launch
    k_gemm2<<<dim3(3, 256, 2), 256, 0, stream>>>(x2h, g2fT, g2bT, g2f_b, g2b_b,
                                                 xg2f, xg2b, 256, G3);
    // 8. GRU2 scan -> h2
    k_gru<<<dim3(4, 2), 1024, 0, stream>>>(xg2f, xg2b, g2f_wh, g2b_wh,
                                           g2f_b, g2b_b, nullptr, h2);
    // 9. dense head
    k_dense<<<1, 64, 0, stream>>>(h2, dense_w, dense_b, out);
}

// Round 13
// 1437.982 us; speedup vs baseline: 1.3106x; 1.3106x over previous
//
#include <hip/hip_runtime.h>
#include <hip/hip_bf16.h>

#define B   64
#define T   512
#define DIN 64
#define F   64
#define U   128
#define G3  384     // 3U
#define M2  256     // 2U
#define NH  4
#define KD  128
#define HD  512     // NH*KD
#define BT  (B*T)   // 32768

typedef __attribute__((ext_vector_type(8))) short short8;
typedef __attribute__((ext_vector_type(4))) float floatx4;
typedef __attribute__((ext_vector_type(4))) unsigned short ushort4_t;
typedef __hip_bfloat16 bf16;

// ---------------- fused weight transpose+cast: 8 segments, one launch ----------------
__device__ __forceinline__ void wcast_seg(const float* __restrict__ src,
        bf16* __restrict__ dst, int K, int N, int i)
{
    if (i < K*N) {
        const int k = i / N, n = i - k*N;
        dst[n*K + k] = __float2bfloat16(src[i]);
    }
}

__global__ __launch_bounds__(256) void k_wcast_all(
        const float* __restrict__ s0, const float* __restrict__ s1,
        const float* __restrict__ s2, const float* __restrict__ s3,
        const float* __restrict__ s4, const float* __restrict__ s5,
        const float* __restrict__ s6, const float* __restrict__ s7,
        bf16* __restrict__ wb)
{
    const int i = blockIdx.x*256 + threadIdx.x;
    switch (blockIdx.y) {
        case 0: wcast_seg(s0, wb,          64,  384, i); break;
        case 1: wcast_seg(s1, wb + 24576,  64,  384, i); break;
        case 2: wcast_seg(s2, wb + 49152,  256, 512, i); break;
        case 3: wcast_seg(s3, wb + 180224, 256, 512, i); break;
        case 4: wcast_seg(s4, wb + 311296, 256, 512, i); break;
        case 5: wcast_seg(s5, wb + 442368, 512, 256, i); break;
        case 6: wcast_seg(s6, wb + 573440, 256, 384, i); break;
        case 7: wcast_seg(s7, wb + 671744, 256, 384, i); break;
    }
}

// ---------------- conv1d(same,k=3) + BN(inference) + ReLU -> bf16 ----------------
__global__ __launch_bounds__(256) void k_conv(const float* __restrict__ in,
        const float* __restrict__ cw, const float* __restrict__ cb,
        const float* __restrict__ gamma, const float* __restrict__ beta,
        const float* __restrict__ mean, const float* __restrict__ var,
        bf16* __restrict__ x1h)
{
    __shared__ float w_s[3*64*64];   // 48 KB
    __shared__ float in_s[18*64];
    const int b  = blockIdx.y;
    const int t0 = blockIdx.x * 16;
    const int tid = threadIdx.x;
    for (int idx = tid; idx < 3*64*64; idx += 256) w_s[idx] = cw[idx];
    for (int idx = tid; idx < 18*64; idx += 256) {
        int row = idx >> 6;
        int d   = idx & 63;
        int t   = t0 - 1 + row;
        in_s[idx] = (t >= 0 && t < T) ? in[((size_t)b*T + t)*DIN + d] : 0.0f;
    }
    __syncthreads();
    const int f  = tid & 63;
    const int tl = tid >> 6;   // 0..3
    const float scale = gamma[f] * rsqrtf(var[f] + 1e-3f);
    const float shift = beta[f] - mean[f] * scale;
    const float bias  = cb[f];
    for (int q = 0; q < 4; ++q) {
        const int tt = tl*4 + q;   // 0..15
        float acc = bias;
        for (int tap = 0; tap < 3; ++tap) {
            const float* irow = &in_s[(tt + tap)*64];
            const float* wrow = &w_s[tap*64*64 + f];
            #pragma unroll 16
            for (int d = 0; d < 64; ++d) acc += irow[d] * wrow[d*64];
        }
        float v = acc * scale + shift;
        x1h[((size_t)b*T + t0 + tt)*F + f] = __float2bfloat16(fmaxf(v, 0.0f));
    }
}

// ------------- MFMA bf16 GEMM: C[R,N] = A[R,K] @ Bt[N,K]^T + bias (+resid) -------------
__global__ __launch_bounds__(256) void k_gemm(const bf16* __restrict__ A,
        const bf16* __restrict__ Bt, const float* __restrict__ bias,
        const bf16* __restrict__ resid, float* __restrict__ outF,
        bf16* __restrict__ outH, int K, int N, int biasRow)
{
    __shared__ short As[128*32];   // 8 KB
    __shared__ short Bs[128*32];   // 8 KB
    const int nbase = blockIdx.x * 128;
    const int rbase = blockIdx.y * 128;
    const int tid  = threadIdx.x;
    const int lane = tid & 63;
    const int wv   = tid >> 6;
    const int wm   = wv & 1;        // row half
    const int wn   = wv >> 1;       // col half
    const int l16  = lane & 15;
    const int quad = lane >> 4;

    floatx4 acc[4][4];
    #pragma unroll
    for (int i = 0; i < 4; ++i)
        #pragma unroll
        for (int j = 0; j < 4; ++j) acc[i][j] = (floatx4)0.0f;

    const int row  = tid >> 1;           // staging: 2 threads per tile-row
    const int koff = (tid & 1) * 16;     // 16 bf16 = 32 B per thread
    const int nK = K >> 5;
    for (int kt = 0; kt < nK; ++kt) {
        if (kt) __syncthreads();
        {
            const float4* ga = reinterpret_cast<const float4*>(
                &A[(size_t)(rbase + row)*K + kt*32 + koff]);
            const float4 a0 = ga[0], a1 = ga[1];
            const float4* gb = reinterpret_cast<const float4*>(
                &Bt[(size_t)(nbase + row)*K + kt*32 + koff]);
            const float4 b0 = gb[0], b1 = gb[1];
            float4* la = reinterpret_cast<float4*>(&As[row*32 + koff]);
            la[0] = a0; la[1] = a1;
            float4* lb = reinterpret_cast<float4*>(&Bs[row*32 + koff]);
            lb[0] = b0; lb[1] = b1;
        }
        __syncthreads();
        short8 af[4], bf[4];
        #pragma unroll
        for (int i = 0; i < 4; ++i)
            af[i] = *reinterpret_cast<const short8*>(&As[(wm*64 + i*16 + l16)*32 + quad*8]);
        #pragma unroll
        for (int j = 0; j < 4; ++j)
            bf[j] = *reinterpret_cast<const short8*>(&Bs[(wn*64 + j*16 + l16)*32 + quad*8]);
        #pragma unroll
        for (int i = 0; i < 4; ++i)
            #pragma unroll
            for (int j = 0; j < 4; ++j)
                acc[i][j] = __builtin_amdgcn_mfma_f32_16x16x32_bf16(af[i], bf[j], acc[i][j], 0, 0, 0);
    }

    #pragma unroll
    for (int j = 0; j < 4; ++j) {
        const int gcol = nbase + wn*64 + j*16 + l16;
        const float bj = biasRow ? 0.0f : bias[gcol];
        #pragma unroll
        for (int i = 0; i < 4; ++i) {
            #pragma unroll
            for (int r = 0; r < 4; ++r) {
                const int grow = rbase + wm*64 + i*16 + quad*4 + r;
                const size_t off = (size_t)grow*N + gcol;
                float v = acc[i][j][r] + (biasRow ? bias[grow] : bj);
                if (resid) v += __bfloat162float(resid[off]);
                if (outF) outF[off] = v;
                if (outH) outH[off] = __float2bfloat16(v);
            }
        }
    }
}

// ------------- paired GEMM: same A, two (Bt, bias, out) sets, blockIdx.z selects -------------
__global__ __launch_bounds__(256) void k_gemm2(const bf16* __restrict__ A,
        const bf16* __restrict__ Bt0, const bf16* __restrict__ Bt1,
        const float* __restrict__ bias0, const float* __restrict__ bias1,
        bf16* __restrict__ out0, bf16* __restrict__ out1, int K, int N)
{
    const bf16* Bt    = blockIdx.z ? Bt1 : Bt0;
    const float* bias = blockIdx.z ? bias1 : bias0;
    bf16* outH        = blockIdx.z ? out1 : out0;

    __shared__ short As[128*32];
    __shared__ short Bs[128*32];
    const int nbase = blockIdx.x * 128;
    const int rbase = blockIdx.y * 128;
    const int tid  = threadIdx.x;
    const int lane = tid & 63;
    const int wv   = tid >> 6;
    const int wm   = wv & 1;
    const int wn   = wv >> 1;
    const int l16  = lane & 15;
    const int quad = lane >> 4;

    floatx4 acc[4][4];
    #pragma unroll
    for (int i = 0; i < 4; ++i)
        #pragma unroll
        for (int j = 0; j < 4; ++j) acc[i][j] = (floatx4)0.0f;

    const int row  = tid >> 1;
    const int koff = (tid & 1) * 16;
    const int nK = K >> 5;
    for (int kt = 0; kt < nK; ++kt) {
        if (kt) __syncthreads();
        {
            const float4* ga = reinterpret_cast<const float4*>(
                &A[(size_t)(rbase + row)*K + kt*32 + koff]);
            const float4 a0 = ga[0], a1 = ga[1];
            const float4* gb = reinterpret_cast<const float4*>(
                &Bt[(size_t)(nbase + row)*K + kt*32 + koff]);
            const float4 b0 = gb[0], b1 = gb[1];
            float4* la = reinterpret_cast<float4*>(&As[row*32 + koff]);
            la[0] = a0; la[1] = a1;
            float4* lb = reinterpret_cast<float4*>(&Bs[row*32 + koff]);
            lb[0] = b0; lb[1] = b1;
        }
        __syncthreads();
        short8 af[4], bf[4];
        #pragma unroll
        for (int i = 0; i < 4; ++i)
            af[i] = *reinterpret_cast<const short8*>(&As[(wm*64 + i*16 + l16)*32 + quad*8]);
        #pragma unroll
        for (int j = 0; j < 4; ++j)
            bf[j] = *reinterpret_cast<const short8*>(&Bs[(wn*64 + j*16 + l16)*32 + quad*8]);
        #pragma unroll
        for (int i = 0; i < 4; ++i)
            #pragma unroll
            for (int j = 0; j < 4; ++j)
                acc[i][j] = __builtin_amdgcn_mfma_f32_16x16x32_bf16(af[i], bf[j], acc[i][j], 0, 0, 0);
    }

    #pragma unroll
    for (int j = 0; j < 4; ++j) {
        const int gcol = nbase + wn*64 + j*16 + l16;
        const float bj = bias[gcol];
        #pragma unroll
        for (int i = 0; i < 4; ++i) {
            #pragma unroll
            for (int r = 0; r < 4; ++r) {
                const int grow = rbase + wm*64 + i*16 + quad*4 + r;
                outH[(size_t)grow*N + gcol] = __float2bfloat16(acc[i][j][r] + bj);
            }
        }
    }
}

// ---------------- MFMA-batched GRU scan (r11-best: 512 thr, frag-order, VALU-diet) ----------------
__device__ __forceinline__ float sigmoidf_(float x){ return 1.0f/(1.0f + __expf(-x)); }
__device__ __forceinline__ float tanhf_(float x){ return 2.0f/(1.0f + __expf(-2.0f*x)) - 1.0f; }
__device__ __forceinline__ float bfbits2f(unsigned short u){
    return __uint_as_float(((unsigned)u) << 16);
}

// Block = 16 batches x 1 dir; grid (4,2) = 8 blocks, 1 chain/CU. 512 thr = 8 waves.
// Measured landscape: 2 chains/CU (r9) = 2x time; 16-wave pair-split (r12) = +53%;
// this 8-wave form = 502 us = the measured optimum of the structure.
// h in FRAGMENT ORDER (2048 shorts/tile): B-frag read = b128 at 16B*(kt*64+lane),
// conflict-free; hnew b64 write lands 4 dwords/bank (minimum). lgkm-only barrier
// (no vmcnt drain: depth-2 xg prefetch + yseq stores stay in flight). Pointer-
// increment xg/yseq streams; recurrent bias rides as MFMA C-operand.
__global__ __launch_bounds__(512, 1) void k_gru(const bf16* __restrict__ xg_f,
        const bf16* __restrict__ xg_b, const float* __restrict__ wh_f,
        const float* __restrict__ wh_b, const float* __restrict__ b_f,
        const float* __restrict__ b_b, bf16* __restrict__ yseq,
        float* __restrict__ hout)
{
    const int dir   = blockIdx.y;
    const int bbase = blockIdx.x * 16;
    const bf16* xg  = dir ? xg_b : xg_f;            // [B*T, 3U]
    const float* wh = dir ? wh_b : wh_f;            // [U, 3U]
    const float* bh = (dir ? b_b : b_f) + G3;       // b[1]
    const int tid  = threadIdx.x;
    const int lane = tid & 63;
    const int wv   = tid >> 6;       // 0..7
    const int l16  = lane & 15;
    const int quad = lane >> 4;
    const int cb   = wv*16 + quad*4; // this lane's 4 gate cols
    const int brow = bbase + l16;    // this lane's batch

    // W^T A-frags, register-resident
    short8 wfrag[3][4];
    #pragma unroll
    for (int g = 0; g < 3; ++g)
        #pragma unroll
        for (int kt = 0; kt < 4; ++kt)
            #pragma unroll
            for (int j = 0; j < 8; ++j)
                reinterpret_cast<bf16*>(&wfrag[g][kt])[j] = __float2bfloat16(
                    wh[(size_t)(kt*32 + quad*8 + j)*G3 + g*U + wv*16 + l16]);

    // recurrent bias as preserved MFMA C-operands
    floatx4 bz4, br4, bn4;
    #pragma unroll
    for (int r = 0; r < 4; ++r) {
        bz4[r] = bh[      cb + r];
        br4[r] = bh[U   + cb + r];
        bn4[r] = bh[2*U + cb + r];
    }

    // write index (shorts) for this lane's b64 hnew store
    const int wr_idx = ((wv>>1)*64 + ((wv&1)*2 + (quad>>1))*16 + l16)*8 + (quad&1)*4;

    __shared__ __align__(16) short hbuf[2][2048];   // [parity][frag order]
    for (int i = tid; i < 2*2048; i += 512) (&hbuf[0][0])[i] = 0;
    __syncthreads();

    float hprev[4] = {0.f, 0.f, 0.f, 0.f};

    // pointer-increment streams (no per-step address math)
    const int t0 = dir ? T-1 : 0;
    const ptrdiff_t xstr = dir ? -(ptrdiff_t)G3 : (ptrdiff_t)G3;
    const ptrdiff_t ystr = dir ? -(ptrdiff_t)M2 : (ptrdiff_t)M2;
    const bf16* xp = xg + ((size_t)brow*T + t0)*G3 + cb;     // next row to LOAD
    bf16* yp = yseq ? (yseq + ((size_t)brow*T + t0)*M2 + dir*U + cb) : nullptr;

    // depth-2 xg prefetch (statically indexed via unroll-2 body)
    ushort4_t xs[2][3];
    #pragma unroll
    for (int s = 0; s < 2; ++s) {
        xs[s][0] = *reinterpret_cast<const ushort4_t*>(xp);
        xs[s][1] = *reinterpret_cast<const ushort4_t*>(xp + U);
        xs[s][2] = *reinterpret_cast<const ushort4_t*>(xp + 2*U);
        xp += xstr;
    }

    for (int step2 = 0; step2 < T; step2 += 2) {
        #pragma unroll
        for (int u = 0; u < 2; ++u) {
            // B-frags: conflict-free lane-contiguous b128 reads
            short8 hfrag[4];
            #pragma unroll
            for (int kt = 0; kt < 4; ++kt)
                hfrag[kt] = *reinterpret_cast<const short8*>(
                    &hbuf[u][(kt*64 + lane)*8]);
            // bias pre-loaded via C-operand of first MFMA
            floatx4 az = __builtin_amdgcn_mfma_f32_16x16x32_bf16(wfrag[0][0], hfrag[0], bz4, 0, 0, 0);
            floatx4 ar = __builtin_amdgcn_mfma_f32_16x16x32_bf16(wfrag[1][0], hfrag[0], br4, 0, 0, 0);
            floatx4 an = __builtin_amdgcn_mfma_f32_16x16x32_bf16(wfrag[2][0], hfrag[0], bn4, 0, 0, 0);
            #pragma unroll
            for (int kt = 1; kt < 4; ++kt) {
                az = __builtin_amdgcn_mfma_f32_16x16x32_bf16(wfrag[0][kt], hfrag[kt], az, 0, 0, 0);
                ar = __builtin_amdgcn_mfma_f32_16x16x32_bf16(wfrag[1][kt], hfrag[kt], ar, 0, 0, 0);
                an = __builtin_amdgcn_mfma_f32_16x16x32_bf16(wfrag[2][kt], hfrag[kt], an, 0, 0, 0);
            }
            // consume this step's xg (loaded 2 steps ago)
            float xzv[4], xrv[4], xnv[4];
            #pragma unroll
            for (int r = 0; r < 4; ++r) {
                xzv[r] = bfbits2f(xs[u][0][r]);
                xrv[r] = bfbits2f(xs[u][1][r]);
                xnv[r] = bfbits2f(xs[u][2][r]);
            }
            // refill slot u for step+2 (free-running pointer; overrun is in-bounds)
            xs[u][0] = *reinterpret_cast<const ushort4_t*>(xp);
            xs[u][1] = *reinterpret_cast<const ushort4_t*>(xp + U);
            xs[u][2] = *reinterpret_cast<const ushort4_t*>(xp + 2*U);
            xp += xstr;
            // gates + state update (batch brow, cols cb..cb+3)
            ushort4_t hpk;
            #pragma unroll
            for (int r = 0; r < 4; ++r) {
                const float z  = sigmoidf_(xzv[r] + az[r]);
                const float rr = sigmoidf_(xrv[r] + ar[r]);
                const float n  = tanhf_(xnv[r] + rr*an[r]);
                const float hnew = z*hprev[r] + (1.0f - z)*n;
                hprev[r] = hnew;
                bf16 hb = __float2bfloat16(hnew);
                hpk[r] = *reinterpret_cast<unsigned short*>(&hb);
            }
            // conflict-free b64 write into next-parity buffer
            *reinterpret_cast<ushort4_t*>(&hbuf[u^1][wr_idx]) = hpk;
            if (yp) {
                *reinterpret_cast<ushort4_t*>(yp) = hpk;
                yp += ystr;
            }
            // LDS-only barrier: wait lgkmcnt(0), leave vmcnt in flight
            asm volatile("" ::: "memory");
            __builtin_amdgcn_s_waitcnt(0xC07F);
            __builtin_amdgcn_s_barrier();
            asm volatile("" ::: "memory");
        }
    }
    if (hout) {
        float4 hv = make_float4(hprev[0], hprev[1], hprev[2], hprev[3]);
        *reinterpret_cast<float4*>(&hout[(size_t)brow*M2 + dir*U + cb]) = hv;
    }
}

// ---------------- MFMA flash attention ----------------
// Q,K,O: [B*T, HD] bf16 (head h at col h*KD). VT: [HD, B*T] bf16 (transposed V).
__global__ __launch_bounds__(256) void k_attn(const bf16* __restrict__ Q,
        const bf16* __restrict__ Kp, const bf16* __restrict__ VT,
        bf16* __restrict__ O)
{
    __shared__ short k_s[64*136];    // 17408 B
    __shared__ short vt_s[128*72];   // 18432 B
    __shared__ short p_s[64*72];     //  9216 B
    const int qt = blockIdx.x;       // 0..7
    const int b  = blockIdx.y;
    const int h  = blockIdx.z;
    const int tid  = threadIdx.x;
    const int lane = tid & 63;
    const int wv   = tid >> 6;
    const int l16  = lane & 15;
    const int quad = lane >> 4;

    short8 qfrag[4];
    {
        const size_t qoff = (size_t)(b*T + qt*64 + wv*16 + l16)*HD + h*KD + quad*8;
        #pragma unroll
        for (int kt = 0; kt < 4; ++kt)
            qfrag[kt] = *reinterpret_cast<const short8*>(&Q[qoff + kt*32]);
    }

    floatx4 Oa[8];
    #pragma unroll
    for (int nf = 0; nf < 8; ++nf) Oa[nf] = (floatx4)0.0f;
    float mrun = -1e30f, lrun = 0.0f;

    for (int kg = 0; kg < 8; ++kg) {
        __syncthreads();
        #pragma unroll
        for (int it = 0; it < 4; ++it) {
            const int linear = it*256 + tid;
            const int key = linear >> 4;
            const int dc  = linear & 15;
            const float4 v = *reinterpret_cast<const float4*>(
                &Kp[(size_t)(b*T + kg*64 + key)*HD + h*KD + dc*8]);
            *reinterpret_cast<float4*>(&k_s[key*136 + dc*8]) = v;
        }
        #pragma unroll
        for (int it = 0; it < 4; ++it) {
            const int linear = it*256 + tid;
            const int d  = linear >> 3;
            const int kc = linear & 7;
            const float4 v = *reinterpret_cast<const float4*>(
                &VT[(size_t)(h*KD + d)*BT + b*T + kg*64 + kc*8]);
            *reinterpret_cast<float4*>(&vt_s[d*72 + kc*8]) = v;
        }
        __syncthreads();
        floatx4 s[4];
        #pragma unroll
        for (int kb = 0; kb < 4; ++kb) s[kb] = (floatx4)0.0f;
        #pragma unroll
        for (int kt = 0; kt < 4; ++kt) {
            #pragma unroll
            for (int kb = 0; kb < 4; ++kb) {
                const short8 af = *reinterpret_cast<const short8*>(
                    &k_s[(kb*16 + l16)*136 + kt*32 + quad*8]);
                s[kb] = __builtin_amdgcn_mfma_f32_16x16x32_bf16(af, qfrag[kt], s[kb], 0, 0, 0);
            }
        }
        float kmax = -1e30f;
        #pragma unroll
        for (int kb = 0; kb < 4; ++kb)
            #pragma unroll
            for (int r = 0; r < 4; ++r) {
                s[kb][r] *= 0.08838834764831845f;
                kmax = fmaxf(kmax, s[kb][r]);
            }
        kmax = fmaxf(kmax, __shfl_xor(kmax, 16));
        kmax = fmaxf(kmax, __shfl_xor(kmax, 32));
        const float mnew  = fmaxf(mrun, kmax);
        const float alpha = __expf(mrun - mnew);
        float psum = 0.0f;
        #pragma unroll
        for (int kb = 0; kb < 4; ++kb)
            #pragma unroll
            for (int r = 0; r < 4; ++r) {
                const float p = __expf(s[kb][r] - mnew);
                s[kb][r] = p;
                psum += p;
            }
        psum += __shfl_xor(psum, 16);
        psum += __shfl_xor(psum, 32);
        lrun = lrun*alpha + psum;
        mrun = mnew;
        #pragma unroll
        for (int r = 0; r < 4; ++r) {
            const float ar = __shfl(alpha, quad*4 + r);
            #pragma unroll
            for (int nf = 0; nf < 8; ++nf) Oa[nf][r] *= ar;
        }
        bf16* pb = reinterpret_cast<bf16*>(p_s);
        #pragma unroll
        for (int kb = 0; kb < 4; ++kb)
            #pragma unroll
            for (int r = 0; r < 4; ++r)
                pb[(wv*16 + l16)*72 + kb*16 + quad*4 + r] = __float2bfloat16(s[kb][r]);
        #pragma unroll
        for (int kt2 = 0; kt2 < 2; ++kt2) {
            const short8 pf = *reinterpret_cast<const short8*>(
                &p_s[(wv*16 + l16)*72 + kt2*32 + quad*8]);
            #pragma unroll
            for (int nf = 0; nf < 8; ++nf) {
                const short8 vf = *reinterpret_cast<const short8*>(
                    &vt_s[(nf*16 + l16)*72 + kt2*32 + quad*8]);
                Oa[nf] = __builtin_amdgcn_mfma_f32_16x16x32_bf16(pf, vf, Oa[nf], 0, 0, 0);
            }
        }
    }
    float linv[4];
    #pragma unroll
    for (int r = 0; r < 4; ++r) linv[r] = 1.0f / __shfl(lrun, quad*4 + r);
    #pragma unroll
    for (int nf = 0; nf < 8; ++nf)
        #pragma unroll
        for (int r = 0; r < 4; ++r) {
            const size_t row = (size_t)(b*T + qt*64 + wv*16 + quad*4 + r);
            O[row*HD + h*KD + nf*16 + l16] = __float2bfloat16(Oa[nf][r] * linv[r]);
        }
}

// ---------------- dense head ----------------
__global__ void k_dense(const float* __restrict__ h2, const float* __restrict__ dw,
                        const float* __restrict__ db, float* __restrict__ out)
{
    const int b = threadIdx.x;
    float acc = db[0];
    for (int mm = 0; mm < M2; ++mm) acc += h2[b*M2 + mm] * dw[mm];
    out[b] = acc;
}

extern "C" void kernel_launch(void* const* d_in, const int* in_sizes, int n_in,
                              void* d_out, int out_size, void* d_ws, size_t ws_size,
                              hipStream_t stream)
{
    const float* inputs  = (const float*)d_in[0];
    const float* conv_w  = (const float*)d_in[1];
    const float* conv_b  = (const float*)d_in[2];
    const float* bn_g    = (const float*)d_in[3];
    const float* bn_b    = (const float*)d_in[4];
    const float* bn_m    = (const float*)d_in[5];
    const float* bn_v    = (const float*)d_in[6];
    const float* g1f_wx  = (const float*)d_in[7];
    const float* g1f_wh  = (const float*)d_in[8];
    const float* g1f_b   = (const float*)d_in[9];
    const float* g1b_wx  = (const float*)d_in[10];
    const float* g1b_wh  = (const float*)d_in[11];
    const float* g1b_b   = (const float*)d_in[12];
    const float* wq      = (const float*)d_in[13];
    const float* bq      = (const float*)d_in[14];
    const float* wk      = (const float*)d_in[15];
    const float* bk      = (const float*)d_in[16];
    const float* wv_     = (const float*)d_in[17];
    const float* bv      = (const float*)d_in[18];
    const float* wo      = (const float*)d_in[19];
    const float* bo      = (const float*)d_in[20];
    const float* g2f_wx  = (const float*)d_in[21];
    const float* g2f_wh  = (const float*)d_in[22];
    const float* g2f_b   = (const float*)d_in[23];
    const float* g2b_wx  = (const float*)d_in[24];
    const float* g2b_wh  = (const float*)d_in[25];
    const float* g2b_b   = (const float*)d_in[26];
    const float* dense_w = (const float*)d_in[27];
    const float* dense_b = (const float*)d_in[28];
    float* out = (float*)d_out;
    (void)in_sizes; (void)n_in; (void)out_size; (void)ws_size;

    // ---- workspace (float-slot offsets into 128 MiB = 33,554,432 fslots) ----
    float* ws = (float*)d_ws;
    bf16* wb = (bf16*)ws;
    bf16* g1fT = wb;            // [384,64]
    bf16* g1bT = wb + 24576;
    bf16* wqT  = wb + 49152;    // [512,256]
    bf16* wkT  = wb + 180224;
    bf16* wvT  = wb + 311296;   // [512,256] -> GEMM-A for V^T
    bf16* woT  = wb + 442368;   // [256,512]
    bf16* g2fT = wb + 573440;   // [384,256]
    bf16* g2bT = wb + 671744;   // ends 770048 < 786432

    bf16*  x1h  = (bf16*)(ws + 393216);     // [B*T,64]
    bf16*  xg1f = (bf16*)(ws + 1441792);    // [B*T,384] bf16
    bf16*  xg1b = (bf16*)(ws + 7733248);    // [B*T,384] bf16
    bf16*  y1h  = (bf16*)(ws + 26607616);   // [B*T,256]
    bf16*  qh   = (bf16*)(ws + 393216);     // [B*T,512]
    bf16*  kh   = (bf16*)(ws + 8781824);    // [B*T,512]
    bf16*  vtg  = (bf16*)(ws + 17170432);   // [512, B*T]
    bf16*  Oh   = qh;                       // attention output in-place
    bf16*  x2h  = (bf16*)(ws + 17170432);   // [B*T,256] (over dead vtg)
    bf16*  xg2f = (bf16*)(ws + 393216);     // [B*T,384]
    bf16*  xg2b = (bf16*)(ws + 6684672);
    float* h2   = ws + 12976128;            // [B,256]

    // 0. fused weight casts (one launch)
    k_wcast_all<<<dim3(512, 8), 256, 0, stream>>>(g1f_wx, g1b_wx, wq, wk, wv_,
                                                  wo, g2f_wx, g2b_wx, wb);

    // 1. conv + BN + ReLU -> x1h
    k_conv<<<dim3(T/16, B), 256, 0, stream>>>(inputs, conv_w, conv_b,
                                              bn_g, bn_b, bn_m, bn_v, x1h);
    // 2. GRU1 input gates, fwd+bwd in one launch
    k_gemm2<<<dim3(3, 256, 2), 256, 0, stream>>>(x1h, g1fT, g1bT, g1f_b, g1b_b,
                                                 xg1f, xg1b, 64, G3);
    // 3. GRU1 scan -> y1h  (r11-best: 512 thr, 1 chain/CU)
    k_gru<<<dim3(4, 2), 512, 0, stream>>>(xg1f, xg1b, g1f_wh, g1b_wh,
                                          g1f_b, g1b_b, y1h, nullptr);
    // 4. Q,K in one launch; V as transposed GEMM
    k_gemm2<<<dim3(4, 256, 2), 256, 0, stream>>>(y1h, wqT, wkT, bq, bk,
                                                 qh, kh, 256, HD);
    k_gemm<<<dim3(BT/128, 4), 256, 0, stream>>>(wvT, y1h, bv, nullptr, nullptr, vtg, 256, BT, 1);
    // 5. MFMA flash attention, O in-place over Q
    k_attn<<<dim3(T/64, B, NH), 256, 0, stream>>>(qh, kh, vtg, Oh);
    // 6. output projection + bias + residual(y1h) -> x2h
    k_gemm<<<dim3(2, 256), 256, 0, stream>>>(Oh, woT, bo, y1h, nullptr, x2h, HD, M2, 0);
    // 7. GRU2 input gates, fwd+bwd in one launch
    k_gemm2<<<dim3(3, 256, 2), 256, 0, stream>>>(x2h, g2fT, g2bT, g2f_b, g2b_b,
                                                 xg2f, xg2b, 256, G3);
    // 8. GRU2 scan -> h2
    k_gru<<<dim3(4, 2), 512, 0, stream>>>(xg2f, xg2b, g2f_wh, g2b_wh,
                                          g2f_b, g2b_b, nullptr, h2);
    // 9. dense head
    k_dense<<<1, 64, 0, stream>>>(h2, dense_w, dense_b, out);
}

// Round 15
// 1391.889 us; speedup vs baseline: 1.3540x; 1.0331x over previous
//
#include <hip/hip_runtime.h>
#include <hip/hip_bf16.h>

#define B   64
#define T   512
#define DIN 64
#define F   64
#define U   128
#define G3  384     // 3U
#define M2  256     // 2U
#define NH  4
#define KD  128
#define HD  512     // NH*KD
#define BT  (B*T)   // 32768

typedef __attribute__((ext_vector_type(8))) short short8;
typedef __attribute__((ext_vector_type(4))) float floatx4;
typedef __attribute__((ext_vector_type(4))) unsigned short ushort4_t;
typedef __hip_bfloat16 bf16;

// ---------------- fused weight transpose+cast: 9 segments + out-init, one launch ----------------
__device__ __forceinline__ void wcast_seg(const float* __restrict__ src,
        bf16* __restrict__ dst, int K, int N, int i)
{
    if (i < K*N) {
        const int k = i / N, n = i - k*N;
        dst[n*K + k] = __float2bfloat16(src[i]);
    }
}

__global__ __launch_bounds__(256) void k_wcast_all(
        const float* __restrict__ s0, const float* __restrict__ s1,
        const float* __restrict__ s2, const float* __restrict__ s3,
        const float* __restrict__ s4, const float* __restrict__ s5,
        const float* __restrict__ s6, const float* __restrict__ s7,
        const float* __restrict__ s8, const float* __restrict__ db,
        float* __restrict__ outp, bf16* __restrict__ wb)
{
    const int i = blockIdx.x*256 + threadIdx.x;
    switch (blockIdx.y) {
        case 0: wcast_seg(s0, wb,          64,  384, i); break;
        case 1: wcast_seg(s1, wb + 24576,  64,  384, i); break;
        case 2: wcast_seg(s2, wb + 49152,  256, 512, i); break;
        case 3: wcast_seg(s3, wb + 180224, 256, 512, i); break;
        case 4: wcast_seg(s4, wb + 311296, 256, 512, i); break;
        case 5: wcast_seg(s5, wb + 442368, 512, 256, i); break;
        case 6: wcast_seg(s6, wb + 573440, 256, 384, i); break;
        case 7: wcast_seg(s7, wb + 671744, 256, 384, i); break;
        case 8: wcast_seg(s8, wb + 770048, 192, 64,  i);   // conv cw [3*64,64] -> cwT [64,192]
                if (blockIdx.x == 0 && threadIdx.x < B) outp[threadIdx.x] = db[0];
                break;
    }
}

// ---------------- fused conv1d+BN+ReLU (MFMA, free im2col) + xg1 f/b GEMMs ----------------
// Block = 128 t-rows of one batch; grid (4, 64); 256 thr = 4 waves.
// Phase 1: x1 = relu((im2col(in) @ cwT^T)*scale + shift2), kept in LDS (pad-72).
//   A-frag addr (m+tap)*72 + (kt&1)*32 + quad*8  (tap = kt>>1, constant per kt) —
//   im2col is pure addressing. Banks: 36 dwords/row = 4 mod 32 -> 2-way (free).
// Phase 2: xg1{f,b} = x1(128x64) @ g1{f,b}T^T, 6 col-tiles of 128, K=64.
__global__ __launch_bounds__(256) void k_conv_xg(const float* __restrict__ in,
        const bf16* __restrict__ cwT, const float* __restrict__ cb,
        const float* __restrict__ gamma, const float* __restrict__ beta,
        const float* __restrict__ mean, const float* __restrict__ var,
        const bf16* __restrict__ g1fT, const bf16* __restrict__ g1bT,
        const float* __restrict__ g1f_b, const float* __restrict__ g1b_b,
        bf16* __restrict__ xg1f, bf16* __restrict__ xg1b)
{
    __shared__ short in_s[130*72];    // 18720 B, bf16 input rows t0-1 .. t0+128
    __shared__ short x1_s[128*72];    // 18432 B, conv output tile
    __shared__ short Bs[128*32];      //  8192 B, weight staging (both phases)
    __shared__ float scale_s[64], shift_s[64];
    const int tc = blockIdx.x;        // t-chunk
    const int b  = blockIdx.y;
    const int t0 = tc*128;
    const int tid  = threadIdx.x;
    const int lane = tid & 63;
    const int wv   = tid >> 6;
    const int l16  = lane & 15;
    const int quad = lane >> 4;

    // stage input rows (fp32 -> bf16), zero-pad out-of-range t
    for (int idx = tid; idx < 130*64; idx += 256) {
        const int row = idx >> 6, d = idx & 63;
        const int t = t0 - 1 + row;
        float v = (t >= 0 && t < T) ? in[((size_t)b*T + t)*DIN + d] : 0.0f;
        bf16 h = __float2bfloat16(v);
        in_s[row*72 + d] = *reinterpret_cast<short*>(&h);
    }
    if (tid < 64) {
        const float sc = gamma[tid] * rsqrtf(var[tid] + 1e-3f);
        scale_s[tid] = sc;
        shift_s[tid] = beta[tid] - mean[tid]*sc + cb[tid]*sc;
    }
    __syncthreads();

    // phase 1: conv GEMM  M=128 (wave: 32 rows), N=64, K=192 (6 kt)
    {
        floatx4 acc[2][4];
        #pragma unroll
        for (int i = 0; i < 2; ++i)
            #pragma unroll
            for (int j = 0; j < 4; ++j) acc[i][j] = (floatx4)0.0f;
        for (int kt = 0; kt < 6; ++kt) {
            __syncthreads();
            {   // stage cwT tile [64 rows][32 k]: 4 thr/row, 8 shorts each
                const int row = tid >> 2, koff = (tid & 3)*8;
                *reinterpret_cast<float4*>(&Bs[row*32 + koff]) =
                    *reinterpret_cast<const float4*>(&cwT[row*192 + kt*32 + koff]);
            }
            __syncthreads();
            const int tap = kt >> 1, d0 = (kt & 1)*32 + quad*8;
            short8 bf[4];
            #pragma unroll
            for (int j = 0; j < 4; ++j)
                bf[j] = *reinterpret_cast<const short8*>(&Bs[(j*16 + l16)*32 + quad*8]);
            #pragma unroll
            for (int i = 0; i < 2; ++i) {
                const short8 af = *reinterpret_cast<const short8*>(
                    &in_s[(wv*32 + i*16 + l16 + tap)*72 + d0]);
                #pragma unroll
                for (int j = 0; j < 4; ++j)
                    acc[i][j] = __builtin_amdgcn_mfma_f32_16x16x32_bf16(af, bf[j], acc[i][j], 0, 0, 0);
            }
        }
        // epilogue: BN+ReLU -> x1_s
        #pragma unroll
        for (int j = 0; j < 4; ++j) {
            const int col = j*16 + l16;
            const float sc = scale_s[col], sh = shift_s[col];
            #pragma unroll
            for (int i = 0; i < 2; ++i)
                #pragma unroll
                for (int r = 0; r < 4; ++r) {
                    const int m = wv*32 + i*16 + quad*4 + r;
                    const float v = fmaxf(acc[i][j][r]*sc + sh, 0.0f);
                    bf16 h = __float2bfloat16(v);
                    x1_s[m*72 + col] = *reinterpret_cast<short*>(&h);
                }
        }
    }
    __syncthreads();

    // phase 2: xg1 = x1 @ g1T^T, 6 col-tiles (0-2: fwd, 3-5: bwd), K=64 (2 kt)
    const int wm = wv & 1, wn = wv >> 1;
    const size_t rbase = (size_t)b*T + t0;
    for (int ct = 0; ct < 6; ++ct) {
        const bf16* Bt = (ct < 3 ? g1fT : g1bT) + (ct % 3)*128*64;
        const float* bias = (ct < 3 ? g1f_b : g1b_b);
        bf16* outp = (ct < 3 ? xg1f : xg1b);
        const int cbase = (ct % 3)*128;
        floatx4 acc[4][4];
        #pragma unroll
        for (int i = 0; i < 4; ++i)
            #pragma unroll
            for (int j = 0; j < 4; ++j) acc[i][j] = (floatx4)0.0f;
        for (int kt = 0; kt < 2; ++kt) {
            __syncthreads();
            {   // stage weight tile [128 rows][32 k]: 2 thr/row, 16 shorts each
                const int row = tid >> 1, koff = (tid & 1)*16;
                const float4* g = reinterpret_cast<const float4*>(&Bt[(size_t)row*64 + kt*32 + koff]);
                float4* l = reinterpret_cast<float4*>(&Bs[row*32 + koff]);
                l[0] = g[0]; l[1] = g[1];
            }
            __syncthreads();
            short8 af[4], bf[4];
            #pragma unroll
            for (int i = 0; i < 4; ++i)
                af[i] = *reinterpret_cast<const short8*>(
                    &x1_s[(wm*64 + i*16 + l16)*72 + kt*32 + quad*8]);
            #pragma unroll
            for (int j = 0; j < 4; ++j)
                bf[j] = *reinterpret_cast<const short8*>(&Bs[(wn*64 + j*16 + l16)*32 + quad*8]);
            #pragma unroll
            for (int i = 0; i < 4; ++i)
                #pragma unroll
                for (int j = 0; j < 4; ++j)
                    acc[i][j] = __builtin_amdgcn_mfma_f32_16x16x32_bf16(af[i], bf[j], acc[i][j], 0, 0, 0);
        }
        #pragma unroll
        for (int j = 0; j < 4; ++j) {
            const int colg = cbase + wn*64 + j*16 + l16;
            const float bj = bias[colg];
            #pragma unroll
            for (int i = 0; i < 4; ++i)
                #pragma unroll
                for (int r = 0; r < 4; ++r) {
                    const int grow = wm*64 + i*16 + quad*4 + r;
                    outp[(rbase + grow)*G3 + colg] = __float2bfloat16(acc[i][j][r] + bj);
                }
        }
    }
}

// ------------- triple GEMM: z=0 Q, z=1 K (row-tiled), z=2 V^T (transposed shape) -------------
__global__ __launch_bounds__(256) void k_gemm3(const bf16* __restrict__ y1h,
        const bf16* __restrict__ wqT, const bf16* __restrict__ wkT,
        const bf16* __restrict__ wvT, const float* __restrict__ bq,
        const float* __restrict__ bk, const float* __restrict__ bv,
        bf16* __restrict__ qh, bf16* __restrict__ kh, bf16* __restrict__ vtg)
{
    const int z = blockIdx.z;
    const bf16* A;  const bf16* Bt;  const float* bias;  bf16* outH;
    int rbase, nbase, N, biasRow;
    if (z < 2) {
        A = y1h;  Bt = z ? wkT : wqT;  bias = z ? bk : bq;  outH = z ? kh : qh;
        rbase = blockIdx.y*128;  nbase = blockIdx.x*128;  N = HD;  biasRow = 0;
    } else {
        A = wvT;  Bt = y1h;  bias = bv;  outH = vtg;
        rbase = blockIdx.x*128;  nbase = blockIdx.y*128;  N = BT;  biasRow = 1;
    }
    const int K = 256;

    __shared__ short As[128*32];
    __shared__ short Bs[128*32];
    const int tid  = threadIdx.x;
    const int lane = tid & 63;
    const int wv   = tid >> 6;
    const int wm   = wv & 1;
    const int wn   = wv >> 1;
    const int l16  = lane & 15;
    const int quad = lane >> 4;

    floatx4 acc[4][4];
    #pragma unroll
    for (int i = 0; i < 4; ++i)
        #pragma unroll
        for (int j = 0; j < 4; ++j) acc[i][j] = (floatx4)0.0f;

    const int row  = tid >> 1;
    const int koff = (tid & 1) * 16;
    for (int kt = 0; kt < 8; ++kt) {
        if (kt) __syncthreads();
        {
            const float4* ga = reinterpret_cast<const float4*>(
                &A[(size_t)(rbase + row)*K + kt*32 + koff]);
            const float4 a0 = ga[0], a1 = ga[1];
            const float4* gb = reinterpret_cast<const float4*>(
                &Bt[(size_t)(nbase + row)*K + kt*32 + koff]);
            const float4 b0 = gb[0], b1 = gb[1];
            float4* la = reinterpret_cast<float4*>(&As[row*32 + koff]);
            la[0] = a0; la[1] = a1;
            float4* lb = reinterpret_cast<float4*>(&Bs[row*32 + koff]);
            lb[0] = b0; lb[1] = b1;
        }
        __syncthreads();
        short8 af[4], bf[4];
        #pragma unroll
        for (int i = 0; i < 4; ++i)
            af[i] = *reinterpret_cast<const short8*>(&As[(wm*64 + i*16 + l16)*32 + quad*8]);
        #pragma unroll
        for (int j = 0; j < 4; ++j)
            bf[j] = *reinterpret_cast<const short8*>(&Bs[(wn*64 + j*16 + l16)*32 + quad*8]);
        #pragma unroll
        for (int i = 0; i < 4; ++i)
            #pragma unroll
            for (int j = 0; j < 4; ++j)
                acc[i][j] = __builtin_amdgcn_mfma_f32_16x16x32_bf16(af[i], bf[j], acc[i][j], 0, 0, 0);
    }
    #pragma unroll
    for (int j = 0; j < 4; ++j) {
        const int gcol = nbase + wn*64 + j*16 + l16;
        const float bj = biasRow ? 0.0f : bias[gcol];
        #pragma unroll
        for (int i = 0; i < 4; ++i)
            #pragma unroll
            for (int r = 0; r < 4; ++r) {
                const int grow = rbase + wm*64 + i*16 + quad*4 + r;
                const float v = acc[i][j][r] + (biasRow ? bias[grow] : bj);
                outH[(size_t)grow*N + gcol] = __float2bfloat16(v);
            }
    }
}

// ---------------- fused wo-projection(+bias+resid) -> LDS -> xg2 f/b GEMMs ----------------
// Block = 64 rows; grid 512. Phase 1: x2(64x256) = Oh(64x512)@woT^T + bo + y1h.
// x2 kept ONLY in LDS (pad-264: 132 dwords = 4 mod 32 -> 2-way reads). Phase 2:
// xg2{f,b}(64x768) = x2 @ g2T^T, 6 col-tiles of 128, K=256.
// (r14 bug fixed here: woT staging wrote 2 float4s of the needed 4 -> half of
//  each Bs row was uninitialized LDS fed to MFMA -> NaN. Now l[0..3]=g[0..3].)
__global__ __launch_bounds__(256) void k_wo_xg2(const bf16* __restrict__ Oh,
        const bf16* __restrict__ woT, const float* __restrict__ bo,
        const bf16* __restrict__ y1h,
        const bf16* __restrict__ g2fT, const bf16* __restrict__ g2bT,
        const float* __restrict__ g2f_b, const float* __restrict__ g2b_b,
        bf16* __restrict__ xg2f, bf16* __restrict__ xg2b)
{
    __shared__ short x2_s[64*264];   // 33792 B
    __shared__ short As[64*32];      //  4096 B
    __shared__ short Bs[256*32];     // 16384 B (phase1 full; phase2 uses first 8 KB)
    const int rbase = blockIdx.x * 64;
    const int tid  = threadIdx.x;
    const int lane = tid & 63;
    const int wv   = tid >> 6;
    const int l16  = lane & 15;
    const int quad = lane >> 4;

    // phase 1: M=64 (wave: 32 rows), N=256 (wave: 128 cols), K=512 (16 kt)
    {
        const int wm = wv & 1, wn = wv >> 1;
        floatx4 acc[2][8];
        #pragma unroll
        for (int i = 0; i < 2; ++i)
            #pragma unroll
            for (int j = 0; j < 8; ++j) acc[i][j] = (floatx4)0.0f;
        for (int kt = 0; kt < 16; ++kt) {
            if (kt) __syncthreads();
            {   // A: 64 rows, 4 thr/row, 8 shorts each
                const int row = tid >> 2, koff = (tid & 3)*8;
                *reinterpret_cast<float4*>(&As[row*32 + koff]) =
                    *reinterpret_cast<const float4*>(&Oh[(size_t)(rbase + row)*HD + kt*32 + koff]);
                // B: woT 256 rows, 1 thr/row, 32 shorts each (4 x float4)
                const float4* g = reinterpret_cast<const float4*>(&woT[(size_t)tid*HD + kt*32]);
                float4* l = reinterpret_cast<float4*>(&Bs[tid*32]);
                l[0] = g[0]; l[1] = g[1]; l[2] = g[2]; l[3] = g[3];
            }
            __syncthreads();
            short8 af[2], bf[8];
            #pragma unroll
            for (int i = 0; i < 2; ++i)
                af[i] = *reinterpret_cast<const short8*>(&As[(wm*32 + i*16 + l16)*32 + quad*8]);
            #pragma unroll
            for (int j = 0; j < 8; ++j)
                bf[j] = *reinterpret_cast<const short8*>(&Bs[(wn*128 + j*16 + l16)*32 + quad*8]);
            #pragma unroll
            for (int i = 0; i < 2; ++i)
                #pragma unroll
                for (int j = 0; j < 8; ++j)
                    acc[i][j] = __builtin_amdgcn_mfma_f32_16x16x32_bf16(af[i], bf[j], acc[i][j], 0, 0, 0);
        }
        // epilogue: + bo + resid(y1h) -> x2_s
        #pragma unroll
        for (int j = 0; j < 8; ++j) {
            const int col = wn*128 + j*16 + l16;
            const float bj = bo[col];
            #pragma unroll
            for (int i = 0; i < 2; ++i)
                #pragma unroll
                for (int r = 0; r < 4; ++r) {
                    const int m = wm*32 + i*16 + quad*4 + r;
                    float v = acc[i][j][r] + bj +
                        __bfloat162float(y1h[(size_t)(rbase + m)*M2 + col]);
                    bf16 h = __float2bfloat16(v);
                    x2_s[m*264 + col] = *reinterpret_cast<short*>(&h);
                }
        }
    }
    __syncthreads();

    // phase 2: 6 col-tiles, M=64 (wave: 32 rows), N=128 (wave: 64 cols), K=256 (8 kt)
    const int wm = wv & 1, wn = wv >> 1;
    for (int ct = 0; ct < 6; ++ct) {
        const bf16* Bt = (ct < 3 ? g2fT : g2bT) + (size_t)(ct % 3)*128*M2;
        const float* bias = (ct < 3 ? g2f_b : g2b_b);
        bf16* outp = (ct < 3 ? xg2f : xg2b);
        const int cbase = (ct % 3)*128;
        floatx4 acc[2][4];
        #pragma unroll
        for (int i = 0; i < 2; ++i)
            #pragma unroll
            for (int j = 0; j < 4; ++j) acc[i][j] = (floatx4)0.0f;
        for (int kt = 0; kt < 8; ++kt) {
            __syncthreads();
            {   // stage weight tile [128 rows][32 k]: 2 thr/row
                const int row = tid >> 1, koff = (tid & 1)*16;
                const float4* g = reinterpret_cast<const float4*>(&Bt[(size_t)row*M2 + kt*32 + koff]);
                float4* l = reinterpret_cast<float4*>(&Bs[row*32 + koff]);
                l[0] = g[0]; l[1] = g[1];
            }
            __syncthreads();
            short8 af[2], bf[4];
            #pragma unroll
            for (int i = 0; i < 2; ++i)
                af[i] = *reinterpret_cast<const short8*>(
                    &x2_s[(wm*32 + i*16 + l16)*264 + kt*32 + quad*8]);
            #pragma unroll
            for (int j = 0; j < 4; ++j)
                bf[j] = *reinterpret_cast<const short8*>(&Bs[(wn*64 + j*16 + l16)*32 + quad*8]);
            #pragma unroll
            for (int i = 0; i < 2; ++i)
                #pragma unroll
                for (int j = 0; j < 4; ++j)
                    acc[i][j] = __builtin_amdgcn_mfma_f32_16x16x32_bf16(af[i], bf[j], acc[i][j], 0, 0, 0);
        }
        #pragma unroll
        for (int j = 0; j < 4; ++j) {
            const int colg = cbase + wn*64 + j*16 + l16;
            const float bj = bias[colg];
            #pragma unroll
            for (int i = 0; i < 2; ++i)
                #pragma unroll
                for (int r = 0; r < 4; ++r) {
                    const int grow = rbase + wm*32 + i*16 + quad*4 + r;
                    outp[(size_t)grow*G3 + colg] = __float2bfloat16(acc[i][j][r] + bj);
                }
        }
    }
}

// ---------------- MFMA-batched GRU scan (r11-best; dense head fused into epilogue) ----------------
__device__ __forceinline__ float sigmoidf_(float x){ return 1.0f/(1.0f + __expf(-x)); }
__device__ __forceinline__ float tanhf_(float x){ return 2.0f/(1.0f + __expf(-2.0f*x)) - 1.0f; }
__device__ __forceinline__ float bfbits2f(unsigned short u){
    return __uint_as_float(((unsigned)u) << 16);
}

__global__ __launch_bounds__(512, 1) void k_gru(const bf16* __restrict__ xg_f,
        const bf16* __restrict__ xg_b, const float* __restrict__ wh_f,
        const float* __restrict__ wh_b, const float* __restrict__ b_f,
        const float* __restrict__ b_b, bf16* __restrict__ yseq,
        const float* __restrict__ dw, float* __restrict__ outp)
{
    const int dir   = blockIdx.y;
    const int bbase = blockIdx.x * 16;
    const bf16* xg  = dir ? xg_b : xg_f;            // [B*T, 3U]
    const float* wh = dir ? wh_b : wh_f;            // [U, 3U]
    const float* bh = (dir ? b_b : b_f) + G3;       // b[1]
    const int tid  = threadIdx.x;
    const int lane = tid & 63;
    const int wv   = tid >> 6;       // 0..7
    const int l16  = lane & 15;
    const int quad = lane >> 4;
    const int cb   = wv*16 + quad*4; // this lane's 4 gate cols
    const int brow = bbase + l16;    // this lane's batch

    short8 wfrag[3][4];
    #pragma unroll
    for (int g = 0; g < 3; ++g)
        #pragma unroll
        for (int kt = 0; kt < 4; ++kt)
            #pragma unroll
            for (int j = 0; j < 8; ++j)
                reinterpret_cast<bf16*>(&wfrag[g][kt])[j] = __float2bfloat16(
                    wh[(size_t)(kt*32 + quad*8 + j)*G3 + g*U + wv*16 + l16]);

    floatx4 bz4, br4, bn4;
    #pragma unroll
    for (int r = 0; r < 4; ++r) {
        bz4[r] = bh[      cb + r];
        br4[r] = bh[U   + cb + r];
        bn4[r] = bh[2*U + cb + r];
    }

    const int wr_idx = ((wv>>1)*64 + ((wv&1)*2 + (quad>>1))*16 + l16)*8 + (quad&1)*4;

    __shared__ __align__(16) short hbuf[2][2048];
    for (int i = tid; i < 2*2048; i += 512) (&hbuf[0][0])[i] = 0;
    __syncthreads();

    float hprev[4] = {0.f, 0.f, 0.f, 0.f};

    const int t0 = dir ? T-1 : 0;
    const ptrdiff_t xstr = dir ? -(ptrdiff_t)G3 : (ptrdiff_t)G3;
    const ptrdiff_t ystr = dir ? -(ptrdiff_t)M2 : (ptrdiff_t)M2;
    const bf16* xp = xg + ((size_t)brow*T + t0)*G3 + cb;
    bf16* yp = yseq ? (yseq + ((size_t)brow*T + t0)*M2 + dir*U + cb) : nullptr;

    ushort4_t xs[2][3];
    #pragma unroll
    for (int s = 0; s < 2; ++s) {
        xs[s][0] = *reinterpret_cast<const ushort4_t*>(xp);
        xs[s][1] = *reinterpret_cast<const ushort4_t*>(xp + U);
        xs[s][2] = *reinterpret_cast<const ushort4_t*>(xp + 2*U);
        xp += xstr;
    }

    for (int step2 = 0; step2 < T; step2 += 2) {
        #pragma unroll
        for (int u = 0; u < 2; ++u) {
            short8 hfrag[4];
            #pragma unroll
            for (int kt = 0; kt < 4; ++kt)
                hfrag[kt] = *reinterpret_cast<const short8*>(
                    &hbuf[u][(kt*64 + lane)*8]);
            floatx4 az = __builtin_amdgcn_mfma_f32_16x16x32_bf16(wfrag[0][0], hfrag[0], bz4, 0, 0, 0);
            floatx4 ar = __builtin_amdgcn_mfma_f32_16x16x32_bf16(wfrag[1][0], hfrag[0], br4, 0, 0, 0);
            floatx4 an = __builtin_amdgcn_mfma_f32_16x16x32_bf16(wfrag[2][0], hfrag[0], bn4, 0, 0, 0);
            #pragma unroll
            for (int kt = 1; kt < 4; ++kt) {
                az = __builtin_amdgcn_mfma_f32_16x16x32_bf16(wfrag[0][kt], hfrag[kt], az, 0, 0, 0);
                ar = __builtin_amdgcn_mfma_f32_16x16x32_bf16(wfrag[1][kt], hfrag[kt], ar, 0, 0, 0);
                an = __builtin_amdgcn_mfma_f32_16x16x32_bf16(wfrag[2][kt], hfrag[kt], an, 0, 0, 0);
            }
            float xzv[4], xrv[4], xnv[4];
            #pragma unroll
            for (int r = 0; r < 4; ++r) {
                xzv[r] = bfbits2f(xs[u][0][r]);
                xrv[r] = bfbits2f(xs[u][1][r]);
                xnv[r] = bfbits2f(xs[u][2][r]);
            }
            xs[u][0] = *reinterpret_cast<const ushort4_t*>(xp);
            xs[u][1] = *reinterpret_cast<const ushort4_t*>(xp + U);
            xs[u][2] = *reinterpret_cast<const ushort4_t*>(xp + 2*U);
            xp += xstr;
            ushort4_t hpk;
            #pragma unroll
            for (int r = 0; r < 4; ++r) {
                const float z  = sigmoidf_(xzv[r] + az[r]);
                const float rr = sigmoidf_(xrv[r] + ar[r]);
                const float n  = tanhf_(xnv[r] + rr*an[r]);
                const float hnew = z*hprev[r] + (1.0f - z)*n;
                hprev[r] = hnew;
                bf16 hb = __float2bfloat16(hnew);
                hpk[r] = *reinterpret_cast<unsigned short*>(&hb);
            }
            *reinterpret_cast<ushort4_t*>(&hbuf[u^1][wr_idx]) = hpk;
            if (yp) {
                *reinterpret_cast<ushort4_t*>(yp) = hpk;
                yp += ystr;
            }
            asm volatile("" ::: "memory");
            __builtin_amdgcn_s_waitcnt(0xC07F);
            __builtin_amdgcn_s_barrier();
            asm volatile("" ::: "memory");
        }
    }
    if (dw) {   // fused dense head: partial dot + device atomicAdd (out pre-inited with db)
        float partial = 0.0f;
        #pragma unroll
        for (int r = 0; r < 4; ++r) partial += hprev[r] * dw[dir*U + cb + r];
        atomicAdd(&outp[brow], partial);
    }
}

// ---------------- MFMA flash attention (unchanged) ----------------
__global__ __launch_bounds__(256) void k_attn(const bf16* __restrict__ Q,
        const bf16* __restrict__ Kp, const bf16* __restrict__ VT,
        bf16* __restrict__ O)
{
    __shared__ short k_s[64*136];
    __shared__ short vt_s[128*72];
    __shared__ short p_s[64*72];
    const int qt = blockIdx.x;
    const int b  = blockIdx.y;
    const int h  = blockIdx.z;
    const int tid  = threadIdx.x;
    const int lane = tid & 63;
    const int wv   = tid >> 6;
    const int l16  = lane & 15;
    const int quad = lane >> 4;

    short8 qfrag[4];
    {
        const size_t qoff = (size_t)(b*T + qt*64 + wv*16 + l16)*HD + h*KD + quad*8;
        #pragma unroll
        for (int kt = 0; kt < 4; ++kt)
            qfrag[kt] = *reinterpret_cast<const short8*>(&Q[qoff + kt*32]);
    }

    floatx4 Oa[8];
    #pragma unroll
    for (int nf = 0; nf < 8; ++nf) Oa[nf] = (floatx4)0.0f;
    float mrun = -1e30f, lrun = 0.0f;

    for (int kg = 0; kg < 8; ++kg) {
        __syncthreads();
        #pragma unroll
        for (int it = 0; it < 4; ++it) {
            const int linear = it*256 + tid;
            const int key = linear >> 4;
            const int dc  = linear & 15;
            const float4 v = *reinterpret_cast<const float4*>(
                &Kp[(size_t)(b*T + kg*64 + key)*HD + h*KD + dc*8]);
            *reinterpret_cast<float4*>(&k_s[key*136 + dc*8]) = v;
        }
        #pragma unroll
        for (int it = 0; it < 4; ++it) {
            const int linear = it*256 + tid;
            const int d  = linear >> 3;
            const int kc = linear & 7;
            const float4 v = *reinterpret_cast<const float4*>(
                &VT[(size_t)(h*KD + d)*BT + b*T + kg*64 + kc*8]);
            *reinterpret_cast<float4*>(&vt_s[d*72 + kc*8]) = v;
        }
        __syncthreads();
        floatx4 s[4];
        #pragma unroll
        for (int kb = 0; kb < 4; ++kb) s[kb] = (floatx4)0.0f;
        #pragma unroll
        for (int kt = 0; kt < 4; ++kt) {
            #pragma unroll
            for (int kb = 0; kb < 4; ++kb) {
                const short8 af = *reinterpret_cast<const short8*>(
                    &k_s[(kb*16 + l16)*136 + kt*32 + quad*8]);
                s[kb] = __builtin_amdgcn_mfma_f32_16x16x32_bf16(af, qfrag[kt], s[kb], 0, 0, 0);
            }
        }
        float kmax = -1e30f;
        #pragma unroll
        for (int kb = 0; kb < 4; ++kb)
            #pragma unroll
            for (int r = 0; r < 4; ++r) {
                s[kb][r] *= 0.08838834764831845f;
                kmax = fmaxf(kmax, s[kb][r]);
            }
        kmax = fmaxf(kmax, __shfl_xor(kmax, 16));
        kmax = fmaxf(kmax, __shfl_xor(kmax, 32));
        const float mnew  = fmaxf(mrun, kmax);
        const float alpha = __expf(mrun - mnew);
        float psum = 0.0f;
        #pragma unroll
        for (int kb = 0; kb < 4; ++kb)
            #pragma unroll
            for (int r = 0; r < 4; ++r) {
                const float p = __expf(s[kb][r] - mnew);
                s[kb][r] = p;
                psum += p;
            }
        psum += __shfl_xor(psum, 16);
        psum += __shfl_xor(psum, 32);
        lrun = lrun*alpha + psum;
        mrun = mnew;
        #pragma unroll
        for (int r = 0; r < 4; ++r) {
            const float ar = __shfl(alpha, quad*4 + r);
            #pragma unroll
            for (int nf = 0; nf < 8; ++nf) Oa[nf][r] *= ar;
        }
        bf16* pb = reinterpret_cast<bf16*>(p_s);
        #pragma unroll
        for (int kb = 0; kb < 4; ++kb)
            #pragma unroll
            for (int r = 0; r < 4; ++r)
                pb[(wv*16 + l16)*72 + kb*16 + quad*4 + r] = __float2bfloat16(s[kb][r]);
        #pragma unroll
        for (int kt2 = 0; kt2 < 2; ++kt2) {
            const short8 pf = *reinterpret_cast<const short8*>(
                &p_s[(wv*16 + l16)*72 + kt2*32 + quad*8]);
            #pragma unroll
            for (int nf = 0; nf < 8; ++nf) {
                const short8 vf = *reinterpret_cast<const short8*>(
                    &vt_s[(nf*16 + l16)*72 + kt2*32 + quad*8]);
                Oa[nf] = __builtin_amdgcn_mfma_f32_16x16x32_bf16(pf, vf, Oa[nf], 0, 0, 0);
            }
        }
    }
    float linv[4];
    #pragma unroll
    for (int r = 0; r < 4; ++r) linv[r] = 1.0f / __shfl(lrun, quad*4 + r);
    #pragma unroll
    for (int nf = 0; nf < 8; ++nf)
        #pragma unroll
        for (int r = 0; r < 4; ++r) {
            const size_t row = (size_t)(b*T + qt*64 + wv*16 + quad*4 + r);
            O[row*HD + h*KD + nf*16 + l16] = __float2bfloat16(Oa[nf][r] * linv[r]);
        }
}

extern "C" void kernel_launch(void* const* d_in, const int* in_sizes, int n_in,
                              void* d_out, int out_size, void* d_ws, size_t ws_size,
                              hipStream_t stream)
{
    const float* inputs  = (const float*)d_in[0];
    const float* conv_w  = (const float*)d_in[1];
    const float* conv_b  = (const float*)d_in[2];
    const float* bn_g    = (const float*)d_in[3];
    const float* bn_b    = (const float*)d_in[4];
    const float* bn_m    = (const float*)d_in[5];
    const float* bn_v    = (const float*)d_in[6];
    const float* g1f_wx  = (const float*)d_in[7];
    const float* g1f_wh  = (const float*)d_in[8];
    const float* g1f_b   = (const float*)d_in[9];
    const float* g1b_wx  = (const float*)d_in[10];
    const float* g1b_wh  = (const float*)d_in[11];
    const float* g1b_b   = (const float*)d_in[12];
    const float* wq      = (const float*)d_in[13];
    const float* bq      = (const float*)d_in[14];
    const float* wk      = (const float*)d_in[15];
    const float* bk      = (const float*)d_in[16];
    const float* wv_     = (const float*)d_in[17];
    const float* bv      = (const float*)d_in[18];
    const float* wo      = (const float*)d_in[19];
    const float* bo      = (const float*)d_in[20];
    const float* g2f_wx  = (const float*)d_in[21];
    const float* g2f_wh  = (const float*)d_in[22];
    const float* g2f_b   = (const float*)d_in[23];
    const float* g2b_wx  = (const float*)d_in[24];
    const float* g2b_wh  = (const float*)d_in[25];
    const float* g2b_b   = (const float*)d_in[26];
    const float* dense_w = (const float*)d_in[27];
    const float* dense_b = (const float*)d_in[28];
    float* out = (float*)d_out;
    (void)in_sizes; (void)n_in; (void)out_size; (void)ws_size;

    // ---- workspace (float-slot offsets into 128 MiB = 33,554,432 fslots) ----
    float* ws = (float*)d_ws;
    bf16* wb = (bf16*)ws;
    bf16* g1fT = wb;            // [384,64]
    bf16* g1bT = wb + 24576;
    bf16* wqT  = wb + 49152;    // [512,256]
    bf16* wkT  = wb + 180224;
    bf16* wvT  = wb + 311296;   // [512,256] -> GEMM-A for V^T
    bf16* woT  = wb + 442368;   // [256,512]
    bf16* g2fT = wb + 573440;   // [384,256]
    bf16* g2bT = wb + 671744;
    bf16* cwT  = wb + 770048;   // [64,192]  ends 782336 < 786432

    bf16*  xg1f = (bf16*)(ws + 1441792);    // [B*T,384] bf16
    bf16*  xg1b = (bf16*)(ws + 7733248);    // [B*T,384] bf16 (ends 14024704)
    bf16*  y1h  = (bf16*)(ws + 26607616);   // [B*T,256]
    bf16*  qh   = (bf16*)(ws + 393216);     // [B*T,512]
    bf16*  kh   = (bf16*)(ws + 8781824);    // [B*T,512]  dead after attn
    bf16*  vtg  = (bf16*)(ws + 17170432);   // [512,B*T]  dead after attn
    bf16*  Oh   = qh;                       // attention output in-place (live in wo_xg2)
    bf16*  xg2f = (bf16*)(ws + 8781824);    // over dead kh  (Oh/y1h NOT aliased)
    bf16*  xg2b = (bf16*)(ws + 17170432);   // over dead vtg

    // 0. fused weight casts + out init (one launch)
    k_wcast_all<<<dim3(512, 9), 256, 0, stream>>>(g1f_wx, g1b_wx, wq, wk, wv_,
                                                  wo, g2f_wx, g2b_wx, conv_w,
                                                  dense_b, out, wb);
    // 1. conv+BN+ReLU (MFMA im2col) + xg1 f/b, fused
    k_conv_xg<<<dim3(4, B), 256, 0, stream>>>(inputs, cwT, conv_b,
                                              bn_g, bn_b, bn_m, bn_v,
                                              g1fT, g1bT, g1f_b, g1b_b, xg1f, xg1b);
    // 2. GRU1 scan -> y1h
    k_gru<<<dim3(4, 2), 512, 0, stream>>>(xg1f, xg1b, g1f_wh, g1b_wh,
                                          g1f_b, g1b_b, y1h, nullptr, nullptr);
    // 3. Q, K, V^T in one launch
    k_gemm3<<<dim3(4, 256, 3), 256, 0, stream>>>(y1h, wqT, wkT, wvT,
                                                 bq, bk, bv, qh, kh, vtg);
    // 4. MFMA flash attention, O in-place over Q
    k_attn<<<dim3(T/64, B, NH), 256, 0, stream>>>(qh, kh, vtg, Oh);
    // 5. wo-projection + bias + resid -> (LDS) -> xg2 f/b, fused
    k_wo_xg2<<<dim3(BT/64), 256, 0, stream>>>(Oh, woT, bo, y1h,
                                              g2fT, g2bT, g2f_b, g2b_b, xg2f, xg2b);
    // 6. GRU2 scan, dense head fused (atomicAdd onto pre-inited out)
    k_gru<<<dim3(4, 2), 512, 0, stream>>>(xg2f, xg2b, g2f_wh, g2b_wh,
                                          g2f_b, g2b_b, nullptr, dense_w, out);
}